// Round 16
// baseline (340.967 us; speedup 1.0000x reference)
//
#include <hip/hip_runtime.h>
#include <math.h>

// N=4, C=256, H=W=32, NH=2, HD=128, MAX_DIS=7, WS=15, WW=225, T=sqrt(128)
// out: [hw=1024][n=4][c=256] fp32
// Round-16 (from round-15 best, 153.8us): mfma_fc fused into scores via
// 2-block handshake. Each fc tile (n, mt16) has exactly 2 producer scores
// blocks (g=0/1); after AG writes + device fence, the SECOND finisher
// (per-tile atomic counter) computes the 16x256 FC tile inline with the
// identical kc-order 3-MFMA scheme -> bit-identical output. fc kernel +
// its launch/latency floor deleted. Counters zeroed by prep each launch.

typedef __attribute__((ext_vector_type(8))) short short8;
typedef __attribute__((ext_vector_type(4))) float floatx4;

__device__ __forceinline__ short f2bf(float f) {
    unsigned u = __float_as_uint(f);
    unsigned r = (u + 0x7fffu + ((u >> 16) & 1u)) >> 16;
    return (short)r;
}
__device__ __forceinline__ float bf2f(short s) {
    return __uint_as_float(((unsigned)(unsigned short)s) << 16);
}

// ---------------------------------------------------------------------------
// prep v5: Wq/Wk/Wv A-frags (384 wave-units, 4/block, grid 96 x 256)
// + block 0 zeroes the 256 fc-handshake counters.
// ---------------------------------------------------------------------------
__global__ __launch_bounds__(256)
void prep(const float* __restrict__ Wq, const float* __restrict__ Wk,
          const float* __restrict__ Wv,
          short* __restrict__ Whi, short* __restrict__ Wlo,
          int* __restrict__ cnt)
{
    const int tid = threadIdx.x;
    if (blockIdx.x == 0) cnt[tid] = 0;

    const int sub = tid >> 6, lane = tid & 63;
    const int n16 = lane & 15, quad = lane >> 4;
    const int u = blockIdx.x * 4 + sub;          // 0..383

    const int sel = u >> 7, rem = u & 127;
    const int dt = rem >> 3, kc = rem & 7;
    const float* W = (sel == 0 ? Wq : sel == 1 ? Wk : Wv);
    const int d = dt * 16 + n16, cb = kc * 32 + quad * 8;
    float4 w0 = *(const float4*)&W[(long)d * 256 + cb];
    float4 w1 = *(const float4*)&W[(long)d * 256 + cb + 4];
    float f[8] = {w0.x, w0.y, w0.z, w0.w, w1.x, w1.y, w1.z, w1.w};
    short8 h8, l8;
#pragma unroll
    for (int j = 0; j < 8; ++j) {
        short hb = f2bf(f[j]);
        h8[j] = hb;
        l8[j] = f2bf(f[j] - bf2f(hb));
    }
    long off = (long)sel * 65536 + (((long)(dt * 8 + kc) * 64) + lane) * 8;
    *(short8*)(Whi + off) = h8;
    *(short8*)(Wlo + off) = l8;
}

// ---------------------------------------------------------------------------
// mfma_proj v10 (round-15 verbatim): coalesced staging; z==12 = constants.
// ---------------------------------------------------------------------------
__global__ __launch_bounds__(256)
void mfma_proj(const float* __restrict__ q, const float* __restrict__ k,
               const float* __restrict__ v,
               const float* __restrict__ Wfc, const float* __restrict__ Wrel,
               const float* __restrict__ Vb,
               short* Whi, short* Wlo,
               const float* __restrict__ bq, const float* __restrict__ bk,
               const float* __restrict__ bv,
               short* __restrict__ qhi, short* __restrict__ qlo,
               short* __restrict__ khi, short* __restrict__ klo,
               short* __restrict__ vhi, short* __restrict__ vlo,
               short* __restrict__ Wrh, short* __restrict__ Wrl,
               short* __restrict__ Vbh, short* __restrict__ Vbl)
{
    __shared__ float st[256 * 17];
    const int tid = threadIdx.x;
    const int wave = tid >> 6, lane = tid & 63;
    const int n16 = lane & 15, quad = lane >> 4;
    const int z = blockIdx.y;

    if (z == 12) {
#pragma unroll
        for (int s = 0; s < 2; ++s) {
            const int u = blockIdx.x * 8 + wave * 2 + s;
            if (u < 128) {
                const int dt = u >> 3, kc = u & 7;
                const int d = dt * 16 + n16, cb = kc * 32 + quad * 8;
                float4 w0 = *(const float4*)&Wfc[(long)d * 256 + cb];
                float4 w1 = *(const float4*)&Wfc[(long)d * 256 + cb + 4];
                float f[8] = {w0.x, w0.y, w0.z, w0.w, w1.x, w1.y, w1.z, w1.w};
                short8 h8, l8;
#pragma unroll
                for (int j = 0; j < 8; ++j) {
                    short hb = f2bf(f[j]);
                    h8[j] = hb;
                    l8[j] = f2bf(f[j] - bf2f(hb));
                }
                long off = (long)3 * 65536 + (((long)(dt * 8 + kc) * 64) + lane) * 8;
                *(short8*)(Whi + off) = h8;
                *(short8*)(Wlo + off) = l8;
            } else if (u < 248) {
                const int t = u - 128;
                const int g = t / 60, r = t - g * 60;
                const int wt = r >> 2, kc = r & 3;
                const int w = wt * 16 + n16;
                const int cb = kc * 32 + quad * 8;
                float f[8] = {0.f, 0.f, 0.f, 0.f, 0.f, 0.f, 0.f, 0.f};
                if (w < 225) {
                    float4 w0 = *(const float4*)&Wrel[(long)(g * 225 + w) * 128 + cb];
                    float4 w1 = *(const float4*)&Wrel[(long)(g * 225 + w) * 128 + cb + 4];
                    f[0] = w0.x; f[1] = w0.y; f[2] = w0.z; f[3] = w0.w;
                    f[4] = w1.x; f[5] = w1.y; f[6] = w1.z; f[7] = w1.w;
                }
                short8 h8, l8;
#pragma unroll
                for (int j = 0; j < 8; ++j) {
                    short hb = f2bf(f[j]);
                    h8[j] = hb;
                    l8[j] = f2bf(f[j] - bf2f(hb));
                }
                long off = (long)g * 30720 + (((long)(wt * 4 + kc) * 64) + lane) * 8;
                *(short8*)(Wrh + off) = h8;
                *(short8*)(Wrl + off) = l8;
            } else if (u < 376) {
                const int t = u - 248;
                const int g = t >> 6, r = t & 63;
                const int dt = r >> 3, wk = r & 7;
                const int ch = dt * 16 + n16;
                const int w0 = wk * 32 + quad * 8;
                float f[8];
#pragma unroll
                for (int j = 0; j < 8; ++j) {
                    int w = w0 + j;
                    f[j] = (w < 225) ? Vb[(long)(g * 128 + ch) * 225 + w] : 0.f;
                }
                short8 h8, l8;
#pragma unroll
                for (int j = 0; j < 8; ++j) {
                    short hb = f2bf(f[j]);
                    h8[j] = hb;
                    l8[j] = f2bf(f[j] - bf2f(hb));
                }
                long off = (((long)(g * 128 + ch)) << 8) + w0;
                *(short8*)(Vbh + off) = h8;
                *(short8*)(Vbl + off) = l8;
            }
        }
        return;
    }

    const int mt16 = blockIdx.x;
    const int sel = z >> 2, batch = z & 3;
    const float* X = (sel == 0 ? q : sel == 1 ? k : v) + ((long)batch << 18);

    // coalesced staging: pass p, thread t -> c = p*64 + (t>>2), m4 = (t&3)*4
    {
#pragma unroll
        for (int p = 0; p < 4; ++p) {
            const int c = p * 64 + (tid >> 2), m4 = (tid & 3) * 4;
            float4 a = *(const float4*)&X[((long)c << 10) + mt16 * 16 + m4];
            float* d = &st[c * 17 + m4];
            d[0] = a.x; d[1] = a.y; d[2] = a.z; d[3] = a.w;
        }
    }

    const float* bias = (sel == 0 ? bq : sel == 1 ? bk : bv);
    float bbv[4][4];
#pragma unroll
    for (int i = 0; i < 4; ++i) {
        float4 b4 = *(const float4*)&bias[(wave * 4 + i) * 16 + quad * 4];
        bbv[i][0] = b4.x; bbv[i][1] = b4.y; bbv[i][2] = b4.z; bbv[i][3] = b4.w;
    }
    __syncthreads();

    floatx4 acc[4] = {{0.f,0.f,0.f,0.f},{0.f,0.f,0.f,0.f},
                      {0.f,0.f,0.f,0.f},{0.f,0.f,0.f,0.f}};
    const long abase = (long)sel * 65536 + (long)lane * 8;
#pragma unroll
    for (int kc = 0; kc < 8; ++kc) {
        short8 bh, bl;
        const float* col = &st[(kc * 32 + quad * 8) * 17 + n16];
#pragma unroll
        for (int j = 0; j < 8; ++j) {
            float f = col[j * 17];
            short hb = f2bf(f);
            bh[j] = hb;
            bl[j] = f2bf(f - bf2f(hb));
        }
#pragma unroll
        for (int i = 0; i < 4; ++i) {
            const int dt = wave * 4 + i;
            short8 ahi = *(const short8*)(Whi + abase + (long)(dt * 8 + kc) * 512);
            short8 alo = *(const short8*)(Wlo + abase + (long)(dt * 8 + kc) * 512);
            acc[i] = __builtin_amdgcn_mfma_f32_16x16x32_bf16(ahi, bh, acc[i], 0, 0, 0);
            acc[i] = __builtin_amdgcn_mfma_f32_16x16x32_bf16(ahi, bl, acc[i], 0, 0, 0);
            acc[i] = __builtin_amdgcn_mfma_f32_16x16x32_bf16(alo, bh, acc[i], 0, 0, 0);
        }
    }

    __syncthreads();
    float* tile = st;
#pragma unroll
    for (int i = 0; i < 4; ++i) {
        const int dt = wave * 4 + i;
#pragma unroll
        for (int r = 0; r < 4; ++r)
            tile[n16 * 257 + dt * 16 + quad * 4 + r] = acc[i][r] + bbv[i][r];
    }
    __syncthreads();

    if (sel == 2) {
        const int gg = tid >> 7, chp = tid & 127;
        const int yq = mt16 >> 1, xb = (mt16 & 1) * 16;
        short8 h0, h1, l0, l1;
#pragma unroll
        for (int j = 0; j < 8; ++j) {
            float f0 = tile[j * 257 + tid];
            float f1 = tile[(j + 8) * 257 + tid];
            short hb0 = f2bf(f0), hb1 = f2bf(f1);
            h0[j] = hb0; l0[j] = f2bf(f0 - bf2f(hb0));
            h1[j] = hb1; l1[j] = f2bf(f1 - bf2f(hb1));
        }
        long o = ((long)((batch * 2 + gg) * 128 + chp) * 32 + yq) * 48 + 8 + xb;
        *(short8*)(vhi + o) = h0;
        *(short8*)(vhi + o + 8) = h1;
        *(short8*)(vlo + o) = l0;
        *(short8*)(vlo + o + 8) = l1;
        const int prow = mt16 >> 1, side = mt16 & 1;
        long po = ((long)((batch * 2 + gg) * 128 + chp) * 32 + prow) * 48 + side * 40;
        short8 zz = {0,0,0,0,0,0,0,0};
        *(short8*)(vhi + po) = zz;
        *(short8*)(vlo + po) = zz;
        return;
    }

    const float scale = (sel == 1) ? 0.08838834764831845f : 1.0f;
    const int m_l = tid >> 4, c16 = (tid & 15) * 16;
    const int m = mt16 * 16 + m_l;
    short* oh = sel ? khi : qhi;
    short* ol = sel ? klo : qlo;
#pragma unroll
    for (int half = 0; half < 2; ++half) {
        const int cg = c16 + half * 8;
        short8 h8, l8;
#pragma unroll
        for (int j = 0; j < 8; ++j) {
            float f = tile[m_l * 257 + cg + j] * scale;
            short hb = f2bf(f);
            h8[j] = hb;
            l8[j] = f2bf(f - bf2f(hb));
        }
        const int g = cg >> 7, ch = cg & 127;
        const long base = (((long)(batch * 2 + g) << 10) + m) * 128 + ch;
        *(short8*)(oh + base) = h8;
        *(short8*)(ol + base) = l8;
    }
}

// ---------------------------------------------------------------------------
// scores_pv (round-22): round-15 kernel + fc-handshake tail.
// After AG writes: threadfence + per-(n,mt16) atomic counter; second
// finisher computes the 16x256 FC tile inline (bit-identical to mfma_fc v2).
// ---------------------------------------------------------------------------
__global__ __launch_bounds__(512)
void scores_pv(const short* __restrict__ qhi, const short* __restrict__ qlo,
               const short* __restrict__ khi, const short* __restrict__ klo,
               const short* __restrict__ Wrh, const short* __restrict__ Wrl,
               const float* __restrict__ brel,
               const short* __restrict__ vhi, const short* __restrict__ vlo,
               const short* __restrict__ Vbh, const short* __restrict__ Vbl,
               const short* __restrict__ Whi, const short* __restrict__ Wlo,
               short* __restrict__ AGhi, short* __restrict__ AGlo,
               const float* __restrict__ bfc, float* __restrict__ out,
               int* __restrict__ cnt)
{
    __shared__ __align__(16) float qk[16 * 241];   // 15.4 KB; aliased as tile[16][133] in F
    __shared__ __align__(16) short pah[16 * 264];  // 8.25 KB
    __shared__ __align__(16) short pal[16 * 264];  // 8.25 KB
    __shared__ float invl[16];
    __shared__ int winner;

    const int tid = threadIdx.x;
    const int wave = tid >> 6, lane = tid & 63;     // wave 0..7
    const int lin = blockIdx.x;
    const int bz  = lin & 7;
    const int yy  = lin >> 3;
    const int y   = yy >> 1;
    const int xt  = yy & 1;
    const int g = bz & 1;
    const int x0 = xt * 16;

    const int n16 = lane & 15, quad = lane >> 4;
    const long qbase = (((long)bz << 10) + y * 32 + x0 + n16) * 128 + quad * 8;
    short8 a_hi[4], a_lo[4];
#pragma unroll
    for (int ch = 0; ch < 4; ++ch) {
        a_hi[ch] = *(const short8*)(qhi + qbase + ch * 32);
        a_lo[ch] = *(const short8*)(qlo + qbase + ch * 32);
    }

    // ---- phase R: rel logits with inline boundary mask ----
    for (int wt = wave; wt < 15; wt += 8) {
        const short* Ah = Wrh + (long)g * 30720 + ((long)(wt * 4) * 64 + lane) * 8;
        const short* Al = Wrl + (long)g * 30720 + ((long)(wt * 4) * 64 + lane) * 8;
        floatx4 racc = {0.f, 0.f, 0.f, 0.f};
#pragma unroll
        for (int kc = 0; kc < 4; ++kc) {
            short8 whh = *(const short8*)(Ah + kc * 512);
            short8 wll = *(const short8*)(Al + kc * 512);
            racc = __builtin_amdgcn_mfma_f32_16x16x32_bf16(whh, a_hi[kc], racc, 0, 0, 0);
            racc = __builtin_amdgcn_mfma_f32_16x16x32_bf16(whh, a_lo[kc], racc, 0, 0, 0);
            racc = __builtin_amdgcn_mfma_f32_16x16x32_bf16(wll, a_hi[kc], racc, 0, 0, 0);
        }
#pragma unroll
        for (int r = 0; r < 4; ++r) {
            int w = wt * 16 + quad * 4 + r;
            if (w < 225) {
                int dy = w / 15, dx = w - dy * 15;
                int hy = y + dy - 7, hx = x0 + n16 + dx - 7;
                bool valid = (hy >= 0) && (hy < 32) && (hx >= 0) && (hx < 32);
                qk[n16 * 241 + dy * 16 + dx] =
                    valid ? (racc[r] + brel[g * 225 + w]) : -1e8f;
            }
        }
    }
    if (tid < 256) {
        int px = tid >> 4, p = tid & 15;
        int slot = (p < 15) ? (p * 16 + 15) : 240;
        qk[px * 241 + slot] = -1e8f;
    }
    __syncthreads();

    // ---- phase B: band QK^T (15 dy over 8 waves) ----
    for (int dy = wave; dy < 15; dy += 8) {
        const int ky = y + dy - 7;
        if (ky < 0 || ky > 31) continue;
#pragma unroll
        for (int kxt = 0; kxt < 2; ++kxt) {
            const int kxg = x0 - 8 + kxt * 16 + n16;
            const long kb = (((long)bz << 10) + ky * 32 + kxg) * 128 + quad * 8;
            floatx4 acc = {0.f, 0.f, 0.f, 0.f};
#pragma unroll
            for (int ch = 0; ch < 4; ++ch) {
                short8 b_hi = *(const short8*)(khi + kb + ch * 32);
                short8 b_lo = *(const short8*)(klo + kb + ch * 32);
                acc = __builtin_amdgcn_mfma_f32_16x16x32_bf16(a_hi[ch], b_hi, acc, 0, 0, 0);
                acc = __builtin_amdgcn_mfma_f32_16x16x32_bf16(a_hi[ch], b_lo, acc, 0, 0, 0);
                acc = __builtin_amdgcn_mfma_f32_16x16x32_bf16(a_lo[ch], b_hi, acc, 0, 0, 0);
            }
            if (kxg >= 0 && kxg < 32) {
#pragma unroll
                for (int r = 0; r < 4; ++r) {
                    int m = quad * 4 + r;
                    int dx = kxg - (x0 + m) + 7;
                    if (dx >= 0 && dx < 15) {
                        int s = m * 241 + dy * 16 + dx;
                        qk[s] = qk[s] + acc[r];
                    }
                }
            }
        }
    }
    __syncthreads();

    // ---- softmax: 32 lanes per px row ----
    {
        int px = tid >> 5, s = tid & 31;
        float mx = -3.0e38f;
        for (int w = s; w < 240; w += 32) mx = fmaxf(mx, qk[px * 241 + w]);
#pragma unroll
        for (int msk = 16; msk; msk >>= 1) mx = fmaxf(mx, __shfl_xor(mx, msk));
        float sum = 0.f;
        for (int w = s; w < 240; w += 32) {
            float p = __expf(qk[px * 241 + w] - mx);
            qk[px * 241 + w] = p;
            sum += p;
        }
#pragma unroll
        for (int msk = 16; msk; msk >>= 1) sum += __shfl_xor(sum, msk);
        if (s == 0) invl[px] = 1.0f / sum;
    }
    __syncthreads();

    // ---- phase T: normalize + bf16 hi/lo into pah/pal ----
    for (int e = tid; e < 4096; e += 512) {
        int px = e >> 8, w = e & 255;
        float p = 0.f;
        if (w < 225) {
            int dy2 = w / 15, dx2 = w - dy2 * 15;
            p = qk[px * 241 + dy2 * 16 + dx2] * invl[px];
        }
        short hb = f2bf(p);
        pah[px * 264 + w] = hb;
        pal[px * 264 + w] = f2bf(p - bf2f(hb));
    }
    __syncthreads();

    // ---- phases A+V: MFMA accumulation, 1 ch-tile per wave ----
    floatx4 acc = {0.f, 0.f, 0.f, 0.f};
    const int ch0 = wave * 16;

#pragma unroll
    for (int wk = 0; wk < 8; ++wk) {
        short8 pa_h = *(const short8*)&pah[n16 * 264 + wk * 32 + quad * 8];
        short8 pa_l = *(const short8*)&pal[n16 * 264 + wk * 32 + quad * 8];
        const long vb0 = (((long)(g * 128 + ch0 + n16)) << 8) + wk * 32 + quad * 8;
        short8 b0h = *(const short8*)(Vbh + vb0);
        short8 b0l = *(const short8*)(Vbl + vb0);
        acc = __builtin_amdgcn_mfma_f32_16x16x32_bf16(pa_h, b0h, acc, 0, 0, 0);
        acc = __builtin_amdgcn_mfma_f32_16x16x32_bf16(pa_h, b0l, acc, 0, 0, 0);
        acc = __builtin_amdgcn_mfma_f32_16x16x32_bf16(pa_l, b0h, acc, 0, 0, 0);
    }

    for (int dy = 0; dy < 15; ++dy) {
        const int ky = y + dy - 7;
        if (ky < 0 || ky > 31) continue;
        short8 bnd_h, bnd_l;
        const int rowoff = n16 * 264 + dy * 15 - n16 - 1;
#pragma unroll
        for (int j = 0; j < 8; ++j) {
            int kk = quad * 8 + j;
            int dx = kk - n16 - 1;
            bool valid = (unsigned)dx < 15u;
            int idx = valid ? (rowoff + kk) : 0;
            short vh = pah[idx];
            short vl = pal[idx];
            bnd_h[j] = valid ? vh : (short)0;
            bnd_l[j] = valid ? vl : (short)0;
        }
        const long v0o = (((long)((bz * 128 + ch0 + n16)) * 32 + ky)) * 48 + x0 + quad * 8;
        short8 v0h = *(const short8*)(vhi + v0o);
        short8 v0l = *(const short8*)(vlo + v0o);
        acc = __builtin_amdgcn_mfma_f32_16x16x32_bf16(bnd_h, v0h, acc, 0, 0, 0);
        acc = __builtin_amdgcn_mfma_f32_16x16x32_bf16(bnd_h, v0l, acc, 0, 0, 0);
        acc = __builtin_amdgcn_mfma_f32_16x16x32_bf16(bnd_l, v0h, acc, 0, 0, 0);
    }

    // ---- phase F: stage tile then AG frag writeback ----
    float* tile = qk;                    // [16][133]
    {
        const int cb = ch0 + n16;
#pragma unroll
        for (int r = 0; r < 4; ++r)
            tile[(quad * 4 + r) * 133 + cb] = acc[r];
    }
    __syncthreads();

    const int nn = bz >> 1;
    const int sub = tid >> 6;
    if (sub < 4) {
        short8 h8, l8;
#pragma unroll
        for (int j = 0; j < 8; ++j) {
            float f = tile[n16 * 133 + sub * 32 + quad * 8 + j];
            short hb = f2bf(f);
            h8[j] = hb;
            l8[j] = f2bf(f - bf2f(hb));
        }
        const int kc = g * 4 + sub;
        long off = (long)nn * 262144 + (((long)(yy * 8 + kc) * 64) + lane) * 8;
        *(short8*)(AGhi + off) = h8;
        *(short8*)(AGlo + off) = l8;
    }

    // ---- handshake: second finisher of (nn, yy) runs the FC tile ----
    __threadfence();
    __syncthreads();
    if (tid == 0) {
        winner = (atomicAdd(&cnt[nn * 64 + yy], 1) == 1) ? 1 : 0;
    }
    __syncthreads();
    if (!winner) return;
    __threadfence();

    // ---- fused FC (bit-identical to mfma_fc v2): 16 dt over 8 waves ----
    const short* Bh = AGhi + (long)nn * 262144;
    const short* Bl = AGlo + (long)nn * 262144;
    const long wbase = (long)3 * 65536 + (long)lane * 8;
    const int dt0 = wave * 2, dt1 = wave * 2 + 1;
    floatx4 fa0 = {0.f, 0.f, 0.f, 0.f};
    floatx4 fa1 = {0.f, 0.f, 0.f, 0.f};
#pragma unroll
    for (int kc = 0; kc < 8; ++kc) {
        const long bo = ((long)(yy * 8 + kc) * 64 + lane) * 8;
        short8 bh = *(const short8*)(Bh + bo);
        short8 bl = *(const short8*)(Bl + bo);
        short8 a0h = *(const short8*)(Whi + wbase + (long)(dt0 * 8 + kc) * 512);
        short8 a0l = *(const short8*)(Wlo + wbase + (long)(dt0 * 8 + kc) * 512);
        fa0 = __builtin_amdgcn_mfma_f32_16x16x32_bf16(a0h, bh, fa0, 0, 0, 0);
        fa0 = __builtin_amdgcn_mfma_f32_16x16x32_bf16(a0h, bl, fa0, 0, 0, 0);
        fa0 = __builtin_amdgcn_mfma_f32_16x16x32_bf16(a0l, bh, fa0, 0, 0, 0);
        short8 a1h = *(const short8*)(Whi + wbase + (long)(dt1 * 8 + kc) * 512);
        short8 a1l = *(const short8*)(Wlo + wbase + (long)(dt1 * 8 + kc) * 512);
        fa1 = __builtin_amdgcn_mfma_f32_16x16x32_bf16(a1h, bh, fa1, 0, 0, 0);
        fa1 = __builtin_amdgcn_mfma_f32_16x16x32_bf16(a1h, bl, fa1, 0, 0, 0);
        fa1 = __builtin_amdgcn_mfma_f32_16x16x32_bf16(a1l, bh, fa1, 0, 0, 0);
    }
    {
        const long ob = (long)(yy * 16 + n16) * 1024 + nn * 256;
        float4 b0 = *(const float4*)&bfc[dt0 * 16 + quad * 4];
        float4 o0 = {fa0[0] + b0.x, fa0[1] + b0.y, fa0[2] + b0.z, fa0[3] + b0.w};
        *(float4*)&out[ob + dt0 * 16 + quad * 4] = o0;
        float4 b1 = *(const float4*)&bfc[dt1 * 16 + quad * 4];
        float4 o1 = {fa1[0] + b1.x, fa1[1] + b1.y, fa1[2] + b1.z, fa1[3] + b1.w};
        *(float4*)&out[ob + dt1 * 16 + quad * 4] = o1;
    }
}

// ---------------------------------------------------------------------------
// ws floats:
//   vhi@2097152 (786432 fl as shorts) vlo@2883584
//   Vbh@4718592 (32768 fl) Vbl@4751360
//   qhi@6561792 qlo@7086080 khi@7610368 klo@8134656 (524288 each)
//   Whi@11804672 (131072, 4 sels) Wlo@11935744
//   AGhi@12066816 (524288) AGlo@12591104
//   Wrh@13115392 (30720) Wrl@13146112
//   cnt@13180928 (256 ints)
// ---------------------------------------------------------------------------
extern "C" void kernel_launch(void* const* d_in, const int* in_sizes, int n_in,
                              void* d_out, int out_size, void* d_ws, size_t ws_size,
                              hipStream_t stream)
{
    const float* q    = (const float*)d_in[0];
    const float* k    = (const float*)d_in[1];
    const float* v    = (const float*)d_in[2];
    const float* Wq   = (const float*)d_in[3];
    const float* bq   = (const float*)d_in[4];
    const float* Wk   = (const float*)d_in[5];
    const float* bk   = (const float*)d_in[6];
    const float* Wv   = (const float*)d_in[7];
    const float* bv   = (const float*)d_in[8];
    const float* Wrel = (const float*)d_in[9];
    const float* brel = (const float*)d_in[10];
    const float* Vb   = (const float*)d_in[11];
    const float* Wfc  = (const float*)d_in[12];
    const float* bfc  = (const float*)d_in[13];
    float* out = (float*)d_out;

    float* ws   = (float*)d_ws;
    short* vhi  = (short*)(ws + 2097152);
    short* vlo  = (short*)(ws + 2883584);
    short* Vbh  = (short*)(ws + 4718592);
    short* Vbl  = (short*)(ws + 4751360);
    short* qhi  = (short*)(ws + 6561792);
    short* qlo  = (short*)(ws + 7086080);
    short* khi  = (short*)(ws + 7610368);
    short* klo  = (short*)(ws + 8134656);
    short* Whi  = (short*)(ws + 11804672);
    short* Wlo  = (short*)(ws + 11935744);
    short* AGhi = (short*)(ws + 12066816);
    short* AGlo = (short*)(ws + 12591104);
    short* Wrh  = (short*)(ws + 13115392);
    short* Wrl  = (short*)(ws + 13146112);
    int*   cnt  = (int*)(ws + 13180928);

    // Wq/Wk/Wv A-frags + zero handshake counters: 96 blocks
    prep<<<dim3(96), dim3(256), 0, stream>>>(Wq, Wk, Wv, Whi, Wlo, cnt);

    // QKV projections (coalesced staging) + constants (z==12): 832 blocks
    mfma_proj<<<dim3(64, 13), dim3(256), 0, stream>>>(q, k, v, Wfc, Wrel, Vb,
                                                      Whi, Wlo,
                                                      bq, bk, bv,
                                                      qhi, qlo, khi, klo,
                                                      vhi, vlo,
                                                      Wrh, Wrl, Vbh, Vbl);

    // rel(+mask) + band QK^T + softmax + MFMA PV + fused FC -> out: 512x512
    scores_pv<<<dim3(512), dim3(512), 0, stream>>>(qhi, qlo, khi, klo,
                                                   Wrh, Wrl, brel,
                                                   vhi, vlo, Vbh, Vbl,
                                                   Whi, Wlo,
                                                   AGhi, AGlo,
                                                   bfc, out, cnt);
}

// Round 17
// 154.491 us; speedup vs baseline: 2.2070x; 2.2070x over previous
//
#include <hip/hip_runtime.h>
#include <math.h>

// N=4, C=256, H=W=32, NH=2, HD=128, MAX_DIS=7, WS=15, WW=225, T=sqrt(128)
// out: [hw=1024][n=4][c=256] fp32
// FINAL (round-15 best, 153.8us): 4-kernel pipeline.
//   prep      : Wq/Wk/Wv A-frags (gates proj).
//   mfma_proj : QKV projection (coalesced staging, pre-converted A-frags);
//               z==12 slice converts Wfc/Wrel/V_bias off the critical chain.
//   scores_pv : rel(+inline mask) + band QK^T + softmax + MFMA PV -> AG frags
//               (512 blocks x 512 threads, XCD-swizzled bz = lin&7).
//   mfma_fc   : FC GEMM -> out (1024 blocks).
// Session evidence: cross-stage fusion via atomics/fences regresses badly on
// MI355X (per-XCD L2 non-coherence makes device fences ~L2-writeback-priced);
// the kernel-launch boundary is the cheapest cross-stage sync.

typedef __attribute__((ext_vector_type(8))) short short8;
typedef __attribute__((ext_vector_type(4))) float floatx4;

__device__ __forceinline__ short f2bf(float f) {
    unsigned u = __float_as_uint(f);
    unsigned r = (u + 0x7fffu + ((u >> 16) & 1u)) >> 16;
    return (short)r;
}
__device__ __forceinline__ float bf2f(short s) {
    return __uint_as_float(((unsigned)(unsigned short)s) << 16);
}

// ---------------------------------------------------------------------------
// prep v4: Wq/Wk/Wv A-frags only (384 wave-units, 4/block, grid 96 x 256).
// ---------------------------------------------------------------------------
__global__ __launch_bounds__(256)
void prep(const float* __restrict__ Wq, const float* __restrict__ Wk,
          const float* __restrict__ Wv,
          short* __restrict__ Whi, short* __restrict__ Wlo)
{
    const int tid = threadIdx.x;
    const int sub = tid >> 6, lane = tid & 63;
    const int n16 = lane & 15, quad = lane >> 4;
    const int u = blockIdx.x * 4 + sub;          // 0..383

    const int sel = u >> 7, rem = u & 127;
    const int dt = rem >> 3, kc = rem & 7;
    const float* W = (sel == 0 ? Wq : sel == 1 ? Wk : Wv);
    const int d = dt * 16 + n16, cb = kc * 32 + quad * 8;
    float4 w0 = *(const float4*)&W[(long)d * 256 + cb];
    float4 w1 = *(const float4*)&W[(long)d * 256 + cb + 4];
    float f[8] = {w0.x, w0.y, w0.z, w0.w, w1.x, w1.y, w1.z, w1.w};
    short8 h8, l8;
#pragma unroll
    for (int j = 0; j < 8; ++j) {
        short hb = f2bf(f[j]);
        h8[j] = hb;
        l8[j] = f2bf(f[j] - bf2f(hb));
    }
    long off = (long)sel * 65536 + (((long)(dt * 8 + kc) * 64) + lane) * 8;
    *(short8*)(Whi + off) = h8;
    *(short8*)(Wlo + off) = l8;
}

// ---------------------------------------------------------------------------
// mfma_proj v10: coalesced staging. grid (64, 13); z<12: sel = z>>2
// (0=q,1=k,2=v), batch = z&3; z==12: constants conversion slice.
// Whi/Wlo passed once (no restrict): z<12 reads sel 0..2, z==12 writes sel 3.
// ---------------------------------------------------------------------------
__global__ __launch_bounds__(256)
void mfma_proj(const float* __restrict__ q, const float* __restrict__ k,
               const float* __restrict__ v,
               const float* __restrict__ Wfc, const float* __restrict__ Wrel,
               const float* __restrict__ Vb,
               short* Whi, short* Wlo,
               const float* __restrict__ bq, const float* __restrict__ bk,
               const float* __restrict__ bv,
               short* __restrict__ qhi, short* __restrict__ qlo,
               short* __restrict__ khi, short* __restrict__ klo,
               short* __restrict__ vhi, short* __restrict__ vlo,
               short* __restrict__ Wrh, short* __restrict__ Wrl,
               short* __restrict__ Vbh, short* __restrict__ Vbl)
{
    __shared__ float st[256 * 17];
    const int tid = threadIdx.x;
    const int wave = tid >> 6, lane = tid & 63;
    const int n16 = lane & 15, quad = lane >> 4;
    const int z = blockIdx.y;

    if (z == 12) {
        // constants conversion: 512 wave-unit capacity, 376 used
#pragma unroll
        for (int s = 0; s < 2; ++s) {
            const int u = blockIdx.x * 8 + wave * 2 + s;
            if (u < 128) {
                const int dt = u >> 3, kc = u & 7;
                const int d = dt * 16 + n16, cb = kc * 32 + quad * 8;
                float4 w0 = *(const float4*)&Wfc[(long)d * 256 + cb];
                float4 w1 = *(const float4*)&Wfc[(long)d * 256 + cb + 4];
                float f[8] = {w0.x, w0.y, w0.z, w0.w, w1.x, w1.y, w1.z, w1.w};
                short8 h8, l8;
#pragma unroll
                for (int j = 0; j < 8; ++j) {
                    short hb = f2bf(f[j]);
                    h8[j] = hb;
                    l8[j] = f2bf(f[j] - bf2f(hb));
                }
                long off = (long)3 * 65536 + (((long)(dt * 8 + kc) * 64) + lane) * 8;
                *(short8*)(Whi + off) = h8;
                *(short8*)(Wlo + off) = l8;
            } else if (u < 248) {
                const int t = u - 128;
                const int g = t / 60, r = t - g * 60;
                const int wt = r >> 2, kc = r & 3;
                const int w = wt * 16 + n16;
                const int cb = kc * 32 + quad * 8;
                float f[8] = {0.f, 0.f, 0.f, 0.f, 0.f, 0.f, 0.f, 0.f};
                if (w < 225) {
                    float4 w0 = *(const float4*)&Wrel[(long)(g * 225 + w) * 128 + cb];
                    float4 w1 = *(const float4*)&Wrel[(long)(g * 225 + w) * 128 + cb + 4];
                    f[0] = w0.x; f[1] = w0.y; f[2] = w0.z; f[3] = w0.w;
                    f[4] = w1.x; f[5] = w1.y; f[6] = w1.z; f[7] = w1.w;
                }
                short8 h8, l8;
#pragma unroll
                for (int j = 0; j < 8; ++j) {
                    short hb = f2bf(f[j]);
                    h8[j] = hb;
                    l8[j] = f2bf(f[j] - bf2f(hb));
                }
                long off = (long)g * 30720 + (((long)(wt * 4 + kc) * 64) + lane) * 8;
                *(short8*)(Wrh + off) = h8;
                *(short8*)(Wrl + off) = l8;
            } else if (u < 376) {
                const int t = u - 248;
                const int g = t >> 6, r = t & 63;
                const int dt = r >> 3, wk = r & 7;
                const int ch = dt * 16 + n16;
                const int w0 = wk * 32 + quad * 8;
                float f[8];
#pragma unroll
                for (int j = 0; j < 8; ++j) {
                    int w = w0 + j;
                    f[j] = (w < 225) ? Vb[(long)(g * 128 + ch) * 225 + w] : 0.f;
                }
                short8 h8, l8;
#pragma unroll
                for (int j = 0; j < 8; ++j) {
                    short hb = f2bf(f[j]);
                    h8[j] = hb;
                    l8[j] = f2bf(f[j] - bf2f(hb));
                }
                long off = (((long)(g * 128 + ch)) << 8) + w0;
                *(short8*)(Vbh + off) = h8;
                *(short8*)(Vbl + off) = l8;
            }
        }
        return;
    }

    const int mt16 = blockIdx.x;
    const int sel = z >> 2, batch = z & 3;
    const float* X = (sel == 0 ? q : sel == 1 ? k : v) + ((long)batch << 18);

    // ---- stage X tile, COALESCED: pass p, thread t -> c = p*64 + (t>>2),
    // m4 = (t&3)*4; lane quads read contiguous 64B. ----
    {
#pragma unroll
        for (int p = 0; p < 4; ++p) {
            const int c = p * 64 + (tid >> 2), m4 = (tid & 3) * 4;
            float4 a = *(const float4*)&X[((long)c << 10) + mt16 * 16 + m4];
            float* d = &st[c * 17 + m4];
            d[0] = a.x; d[1] = a.y; d[2] = a.z; d[3] = a.w;
        }
    }

    const float* bias = (sel == 0 ? bq : sel == 1 ? bk : bv);
    float bbv[4][4];
#pragma unroll
    for (int i = 0; i < 4; ++i) {
        float4 b4 = *(const float4*)&bias[(wave * 4 + i) * 16 + quad * 4];
        bbv[i][0] = b4.x; bbv[i][1] = b4.y; bbv[i][2] = b4.z; bbv[i][3] = b4.w;
    }
    __syncthreads();

    floatx4 acc[4] = {{0.f,0.f,0.f,0.f},{0.f,0.f,0.f,0.f},
                      {0.f,0.f,0.f,0.f},{0.f,0.f,0.f,0.f}};
    const long abase = (long)sel * 65536 + (long)lane * 8;
#pragma unroll
    for (int kc = 0; kc < 8; ++kc) {
        short8 bh, bl;
        const float* col = &st[(kc * 32 + quad * 8) * 17 + n16];
#pragma unroll
        for (int j = 0; j < 8; ++j) {
            float f = col[j * 17];
            short hb = f2bf(f);
            bh[j] = hb;
            bl[j] = f2bf(f - bf2f(hb));
        }
#pragma unroll
        for (int i = 0; i < 4; ++i) {
            const int dt = wave * 4 + i;
            short8 ahi = *(const short8*)(Whi + abase + (long)(dt * 8 + kc) * 512);
            short8 alo = *(const short8*)(Wlo + abase + (long)(dt * 8 + kc) * 512);
            acc[i] = __builtin_amdgcn_mfma_f32_16x16x32_bf16(ahi, bh, acc[i], 0, 0, 0);
            acc[i] = __builtin_amdgcn_mfma_f32_16x16x32_bf16(ahi, bl, acc[i], 0, 0, 0);
            acc[i] = __builtin_amdgcn_mfma_f32_16x16x32_bf16(alo, bh, acc[i], 0, 0, 0);
        }
    }

    __syncthreads();
    float* tile = st;
#pragma unroll
    for (int i = 0; i < 4; ++i) {
        const int dt = wave * 4 + i;
#pragma unroll
        for (int r = 0; r < 4; ++r)
            tile[n16 * 257 + dt * 16 + quad * 4 + r] = acc[i][r] + bbv[i][r];
    }
    __syncthreads();

    if (sel == 2) {
        const int gg = tid >> 7, chp = tid & 127;
        const int yq = mt16 >> 1, xb = (mt16 & 1) * 16;
        short8 h0, h1, l0, l1;
#pragma unroll
        for (int j = 0; j < 8; ++j) {
            float f0 = tile[j * 257 + tid];
            float f1 = tile[(j + 8) * 257 + tid];
            short hb0 = f2bf(f0), hb1 = f2bf(f1);
            h0[j] = hb0; l0[j] = f2bf(f0 - bf2f(hb0));
            h1[j] = hb1; l1[j] = f2bf(f1 - bf2f(hb1));
        }
        long o = ((long)((batch * 2 + gg) * 128 + chp) * 32 + yq) * 48 + 8 + xb;
        *(short8*)(vhi + o) = h0;
        *(short8*)(vhi + o + 8) = h1;
        *(short8*)(vlo + o) = l0;
        *(short8*)(vlo + o + 8) = l1;
        const int prow = mt16 >> 1, side = mt16 & 1;
        long po = ((long)((batch * 2 + gg) * 128 + chp) * 32 + prow) * 48 + side * 40;
        short8 zz = {0,0,0,0,0,0,0,0};
        *(short8*)(vhi + po) = zz;
        *(short8*)(vlo + po) = zz;
        return;
    }

    const float scale = (sel == 1) ? 0.08838834764831845f : 1.0f;
    const int m_l = tid >> 4, c16 = (tid & 15) * 16;
    const int m = mt16 * 16 + m_l;
    short* oh = sel ? khi : qhi;
    short* ol = sel ? klo : qlo;
#pragma unroll
    for (int half = 0; half < 2; ++half) {
        const int cg = c16 + half * 8;
        short8 h8, l8;
#pragma unroll
        for (int j = 0; j < 8; ++j) {
            float f = tile[m_l * 257 + cg + j] * scale;
            short hb = f2bf(f);
            h8[j] = hb;
            l8[j] = f2bf(f - bf2f(hb));
        }
        const int g = cg >> 7, ch = cg & 127;
        const long base = (((long)(batch * 2 + g) << 10) + m) * 128 + ch;
        *(short8*)(oh + base) = h8;
        *(short8*)(ol + base) = l8;
    }
}

// ---------------------------------------------------------------------------
// scores_pv: 512 px-tiles x 512 threads, M folded into R (6 barriers).
// ---------------------------------------------------------------------------
__global__ __launch_bounds__(512)
void scores_pv(const short* __restrict__ qhi, const short* __restrict__ qlo,
               const short* __restrict__ khi, const short* __restrict__ klo,
               const short* __restrict__ Wrh, const short* __restrict__ Wrl,
               const float* __restrict__ brel,
               const short* __restrict__ vhi, const short* __restrict__ vlo,
               const short* __restrict__ Vbh, const short* __restrict__ Vbl,
               short* __restrict__ AGhi, short* __restrict__ AGlo)
{
    __shared__ __align__(16) float qk[16 * 241];   // 15.4 KB; aliased as tile[16][133] in F
    __shared__ __align__(16) short pah[16 * 264];  // 8.25 KB
    __shared__ __align__(16) short pal[16 * 264];  // 8.25 KB
    __shared__ float invl[16];

    const int tid = threadIdx.x;
    const int wave = tid >> 6, lane = tid & 63;     // wave 0..7
    const int lin = blockIdx.x;
    const int bz  = lin & 7;
    const int yy  = lin >> 3;
    const int y   = yy >> 1;
    const int xt  = yy & 1;
    const int g = bz & 1;
    const int x0 = xt * 16;

    const int n16 = lane & 15, quad = lane >> 4;
    const long qbase = (((long)bz << 10) + y * 32 + x0 + n16) * 128 + quad * 8;
    short8 a_hi[4], a_lo[4];
#pragma unroll
    for (int ch = 0; ch < 4; ++ch) {
        a_hi[ch] = *(const short8*)(qhi + qbase + ch * 32);
        a_lo[ch] = *(const short8*)(qlo + qbase + ch * 32);
    }

    // ---- phase R: rel logits with inline boundary mask ----
    for (int wt = wave; wt < 15; wt += 8) {
        const short* Ah = Wrh + (long)g * 30720 + ((long)(wt * 4) * 64 + lane) * 8;
        const short* Al = Wrl + (long)g * 30720 + ((long)(wt * 4) * 64 + lane) * 8;
        floatx4 racc = {0.f, 0.f, 0.f, 0.f};
#pragma unroll
        for (int kc = 0; kc < 4; ++kc) {
            short8 whh = *(const short8*)(Ah + kc * 512);
            short8 wll = *(const short8*)(Al + kc * 512);
            racc = __builtin_amdgcn_mfma_f32_16x16x32_bf16(whh, a_hi[kc], racc, 0, 0, 0);
            racc = __builtin_amdgcn_mfma_f32_16x16x32_bf16(whh, a_lo[kc], racc, 0, 0, 0);
            racc = __builtin_amdgcn_mfma_f32_16x16x32_bf16(wll, a_hi[kc], racc, 0, 0, 0);
        }
#pragma unroll
        for (int r = 0; r < 4; ++r) {
            int w = wt * 16 + quad * 4 + r;
            if (w < 225) {
                int dy = w / 15, dx = w - dy * 15;
                int hy = y + dy - 7, hx = x0 + n16 + dx - 7;
                bool valid = (hy >= 0) && (hy < 32) && (hx >= 0) && (hx < 32);
                qk[n16 * 241 + dy * 16 + dx] =
                    valid ? (racc[r] + brel[g * 225 + w]) : -1e8f;
            }
        }
    }
    if (tid < 256) {
        int px = tid >> 4, p = tid & 15;
        int slot = (p < 15) ? (p * 16 + 15) : 240;
        qk[px * 241 + slot] = -1e8f;
    }
    __syncthreads();

    // ---- phase B: band QK^T (15 dy over 8 waves) ----
    for (int dy = wave; dy < 15; dy += 8) {
        const int ky = y + dy - 7;
        if (ky < 0 || ky > 31) continue;
#pragma unroll
        for (int kxt = 0; kxt < 2; ++kxt) {
            const int kxg = x0 - 8 + kxt * 16 + n16;
            const long kb = (((long)bz << 10) + ky * 32 + kxg) * 128 + quad * 8;
            floatx4 acc = {0.f, 0.f, 0.f, 0.f};
#pragma unroll
            for (int ch = 0; ch < 4; ++ch) {
                short8 b_hi = *(const short8*)(khi + kb + ch * 32);
                short8 b_lo = *(const short8*)(klo + kb + ch * 32);
                acc = __builtin_amdgcn_mfma_f32_16x16x32_bf16(a_hi[ch], b_hi, acc, 0, 0, 0);
                acc = __builtin_amdgcn_mfma_f32_16x16x32_bf16(a_hi[ch], b_lo, acc, 0, 0, 0);
                acc = __builtin_amdgcn_mfma_f32_16x16x32_bf16(a_lo[ch], b_hi, acc, 0, 0, 0);
            }
            if (kxg >= 0 && kxg < 32) {
#pragma unroll
                for (int r = 0; r < 4; ++r) {
                    int m = quad * 4 + r;
                    int dx = kxg - (x0 + m) + 7;
                    if (dx >= 0 && dx < 15) {
                        int s = m * 241 + dy * 16 + dx;
                        qk[s] = qk[s] + acc[r];
                    }
                }
            }
        }
    }
    __syncthreads();

    // ---- softmax: 32 lanes per px row ----
    {
        int px = tid >> 5, s = tid & 31;
        float mx = -3.0e38f;
        for (int w = s; w < 240; w += 32) mx = fmaxf(mx, qk[px * 241 + w]);
#pragma unroll
        for (int msk = 16; msk; msk >>= 1) mx = fmaxf(mx, __shfl_xor(mx, msk));
        float sum = 0.f;
        for (int w = s; w < 240; w += 32) {
            float p = __expf(qk[px * 241 + w] - mx);
            qk[px * 241 + w] = p;
            sum += p;
        }
#pragma unroll
        for (int msk = 16; msk; msk >>= 1) sum += __shfl_xor(sum, msk);
        if (s == 0) invl[px] = 1.0f / sum;
    }
    __syncthreads();

    // ---- phase T: normalize + bf16 hi/lo into pah/pal (w >= 225 -> 0) ----
    for (int e = tid; e < 4096; e += 512) {
        int px = e >> 8, w = e & 255;
        float p = 0.f;
        if (w < 225) {
            int dy2 = w / 15, dx2 = w - dy2 * 15;
            p = qk[px * 241 + dy2 * 16 + dx2] * invl[px];
        }
        short hb = f2bf(p);
        pah[px * 264 + w] = hb;
        pal[px * 264 + w] = f2bf(p - bf2f(hb));
    }
    __syncthreads();

    // ---- phases A+V: MFMA accumulation, 1 ch-tile per wave (8 tiles) ----
    floatx4 acc = {0.f, 0.f, 0.f, 0.f};
    const int ch0 = wave * 16;

#pragma unroll
    for (int wk = 0; wk < 8; ++wk) {
        short8 pa_h = *(const short8*)&pah[n16 * 264 + wk * 32 + quad * 8];
        short8 pa_l = *(const short8*)&pal[n16 * 264 + wk * 32 + quad * 8];
        const long vb0 = (((long)(g * 128 + ch0 + n16)) << 8) + wk * 32 + quad * 8;
        short8 b0h = *(const short8*)(Vbh + vb0);
        short8 b0l = *(const short8*)(Vbl + vb0);
        acc = __builtin_amdgcn_mfma_f32_16x16x32_bf16(pa_h, b0h, acc, 0, 0, 0);
        acc = __builtin_amdgcn_mfma_f32_16x16x32_bf16(pa_h, b0l, acc, 0, 0, 0);
        acc = __builtin_amdgcn_mfma_f32_16x16x32_bf16(pa_l, b0h, acc, 0, 0, 0);
    }

    for (int dy = 0; dy < 15; ++dy) {
        const int ky = y + dy - 7;
        if (ky < 0 || ky > 31) continue;
        short8 bnd_h, bnd_l;
        const int rowoff = n16 * 264 + dy * 15 - n16 - 1;
#pragma unroll
        for (int j = 0; j < 8; ++j) {
            int kk = quad * 8 + j;
            int dx = kk - n16 - 1;
            bool valid = (unsigned)dx < 15u;
            int idx = valid ? (rowoff + kk) : 0;
            short vh = pah[idx];
            short vl = pal[idx];
            bnd_h[j] = valid ? vh : (short)0;
            bnd_l[j] = valid ? vl : (short)0;
        }
        const long v0o = (((long)((bz * 128 + ch0 + n16)) * 32 + ky)) * 48 + x0 + quad * 8;
        short8 v0h = *(const short8*)(vhi + v0o);
        short8 v0l = *(const short8*)(vlo + v0o);
        acc = __builtin_amdgcn_mfma_f32_16x16x32_bf16(bnd_h, v0h, acc, 0, 0, 0);
        acc = __builtin_amdgcn_mfma_f32_16x16x32_bf16(bnd_h, v0l, acc, 0, 0, 0);
        acc = __builtin_amdgcn_mfma_f32_16x16x32_bf16(bnd_l, v0h, acc, 0, 0, 0);
    }

    // ---- phase F: stage tile [16 px][128 ch] then AG frag conversion ----
    float* tile = qk;                    // [16][133]
    {
        const int cb = ch0 + n16;
#pragma unroll
        for (int r = 0; r < 4; ++r)
            tile[(quad * 4 + r) * 133 + cb] = acc[r];
    }
    __syncthreads();

    const int sub = tid >> 6;
    if (sub < 4) {
        short8 h8, l8;
#pragma unroll
        for (int j = 0; j < 8; ++j) {
            float f = tile[n16 * 133 + sub * 32 + quad * 8 + j];
            short hb = f2bf(f);
            h8[j] = hb;
            l8[j] = f2bf(f - bf2f(hb));
        }
        const int n = bz >> 1;
        const int mt16 = y * 2 + xt;
        const int kc = g * 4 + sub;
        long off = (long)n * 262144 + (((long)(mt16 * 8 + kc) * 64) + lane) * 8;
        *(short8*)(AGhi + off) = h8;
        *(short8*)(AGlo + off) = l8;
    }
}

// ---------------------------------------------------------------------------
// mfma_fc v2: one d-tile per wave. grid (mt16 64, db 4, nz 4) = 1024 blocks.
// ---------------------------------------------------------------------------
__global__ __launch_bounds__(256)
void mfma_fc(const short* __restrict__ Ahi, const short* __restrict__ Alo,
             const short* __restrict__ Whi, const short* __restrict__ Wlo,
             const float* __restrict__ bfc, float* __restrict__ out)
{
    __shared__ float tile[16 * 68];
    const int tid = threadIdx.x;
    const int wave = tid >> 6, lane = tid & 63;
    const int n16 = lane & 15, quad = lane >> 4;
    const int mt16 = blockIdx.x, db = blockIdx.y, nz = blockIdx.z;
    const int dt = db * 4 + wave;

    const short* Ah = Whi + (long)3 * 65536 + ((long)(dt * 8) * 64 + lane) * 8;
    const short* Al = Wlo + (long)3 * 65536 + ((long)(dt * 8) * 64 + lane) * 8;
    const short* Bh = Ahi + (long)nz * 262144;
    const short* Bl = Alo + (long)nz * 262144;

    float4 bv4 = *(const float4*)&bfc[dt * 16 + quad * 4];
    float bb[4] = {bv4.x, bv4.y, bv4.z, bv4.w};

    floatx4 acc = {0.f, 0.f, 0.f, 0.f};
#pragma unroll
    for (int kc = 0; kc < 8; ++kc) {
        short8 ahi = *(const short8*)(Ah + kc * 512);
        short8 alo = *(const short8*)(Al + kc * 512);
        long bo = ((long)(mt16 * 8 + kc) * 64 + lane) * 8;
        short8 bh = *(const short8*)(Bh + bo);
        short8 bl = *(const short8*)(Bl + bo);
        acc = __builtin_amdgcn_mfma_f32_16x16x32_bf16(ahi, bh, acc, 0, 0, 0);
        acc = __builtin_amdgcn_mfma_f32_16x16x32_bf16(ahi, bl, acc, 0, 0, 0);
        acc = __builtin_amdgcn_mfma_f32_16x16x32_bf16(alo, bh, acc, 0, 0, 0);
    }

    const int dl = wave * 16 + quad * 4;
#pragma unroll
    for (int r = 0; r < 4; ++r)
        tile[n16 * 68 + dl + r] = acc[r] + bb[r];
    __syncthreads();

    const int mm = tid >> 4, d4 = (tid & 15) * 4;
    float4 o4 = *(const float4*)&tile[mm * 68 + d4];
    *(float4*)&out[(long)(mt16 * 16 + mm) * 1024 + nz * 256 + db * 64 + d4] = o4;
}

// ---------------------------------------------------------------------------
// ws floats:
//   vhi@2097152 (786432 fl as shorts) vlo@2883584
//   Vbh@4718592 (32768 fl) Vbl@4751360
//   qhi@6561792 qlo@7086080 khi@7610368 klo@8134656 (524288 each)
//   Whi@11804672 (131072, 4 sels) Wlo@11935744
//   AGhi@12066816 (524288) AGlo@12591104
//   Wrh@13115392 (30720) Wrl@13146112
// ---------------------------------------------------------------------------
extern "C" void kernel_launch(void* const* d_in, const int* in_sizes, int n_in,
                              void* d_out, int out_size, void* d_ws, size_t ws_size,
                              hipStream_t stream)
{
    const float* q    = (const float*)d_in[0];
    const float* k    = (const float*)d_in[1];
    const float* v    = (const float*)d_in[2];
    const float* Wq   = (const float*)d_in[3];
    const float* bq   = (const float*)d_in[4];
    const float* Wk   = (const float*)d_in[5];
    const float* bk   = (const float*)d_in[6];
    const float* Wv   = (const float*)d_in[7];
    const float* bv   = (const float*)d_in[8];
    const float* Wrel = (const float*)d_in[9];
    const float* brel = (const float*)d_in[10];
    const float* Vb   = (const float*)d_in[11];
    const float* Wfc  = (const float*)d_in[12];
    const float* bfc  = (const float*)d_in[13];
    float* out = (float*)d_out;

    float* ws   = (float*)d_ws;
    short* vhi  = (short*)(ws + 2097152);
    short* vlo  = (short*)(ws + 2883584);
    short* Vbh  = (short*)(ws + 4718592);
    short* Vbl  = (short*)(ws + 4751360);
    short* qhi  = (short*)(ws + 6561792);
    short* qlo  = (short*)(ws + 7086080);
    short* khi  = (short*)(ws + 7610368);
    short* klo  = (short*)(ws + 8134656);
    short* Whi  = (short*)(ws + 11804672);
    short* Wlo  = (short*)(ws + 11935744);
    short* AGhi = (short*)(ws + 12066816);
    short* AGlo = (short*)(ws + 12591104);
    short* Wrh  = (short*)(ws + 13115392);
    short* Wrl  = (short*)(ws + 13146112);

    // Wq/Wk/Wv A-frags only (gates proj): 96 blocks
    prep<<<dim3(96), dim3(256), 0, stream>>>(Wq, Wk, Wv, Whi, Wlo);

    // QKV projections (coalesced staging) + constants (z==12): 832 blocks
    mfma_proj<<<dim3(64, 13), dim3(256), 0, stream>>>(q, k, v, Wfc, Wrel, Vb,
                                                      Whi, Wlo,
                                                      bq, bk, bv,
                                                      qhi, qlo, khi, klo,
                                                      vhi, vlo,
                                                      Wrh, Wrl, Vbh, Vbl);

    // rel(+mask) + band QK^T + softmax + MFMA PV -> AG frags: 512 x 512
    scores_pv<<<dim3(512), dim3(512), 0, stream>>>(qhi, qlo, khi, klo,
                                                   Wrh, Wrl, brel,
                                                   vhi, vlo, Vbh, Vbl,
                                                   AGhi, AGlo);

    // FC via MFMA: 1024 blocks (4/CU)
    mfma_fc<<<dim3(64, 4, 4), dim3(256), 0, stream>>>(AGhi, AGlo, Whi, Wlo,
                                                      bfc, out);
}